// Round 9
// baseline (39.082 us; speedup 1.0000x reference)
//
#include <hip/hip_runtime.h>
#include <stdint.h>

// Dynamic 3x3 softmax-weighted conv, reflect padding — two-pass version.
// x: (4, 64, 256, 256) f32, kernel: (4, 9, 256, 256) f32, out: (4, 64, 256, 256) f32
// Pass 1: ws[b,j,h,w] = softmax_j(kernel[b,:,h,w])        (9.4 MB)
// Pass 2: out[b,c,h,w] = sum_j ws[b,j,h,w] * x_reflect[...]

constexpr int BATCH = 4;
constexpr int CHAN  = 64;
constexpr int HH    = 256;
constexpr int WW    = 256;
constexpr int CG    = 4;        // channels per block (pass 2)
constexpr int RPB   = 4;        // output rows per block (one wave per row)
constexpr int NROW  = RPB + 2;  // staged input rows per channel
constexpr long WS_ELEMS = (long)BATCH * 9 * HH * WW;   // 2359296 floats = 9.4 MB

typedef float vf4 __attribute__((ext_vector_type(4)));
typedef const __attribute__((address_space(1))) void* gas_ptr;
typedef __attribute__((address_space(3))) void* las_ptr;

// ---------------- pass 1: softmax over the 9 taps ----------------
__global__ __launch_bounds__(256) void softmax_kernel(
    const float* __restrict__ ker, float* __restrict__ wsw)
{
    const int tid = blockIdx.x * 256 + threadIdx.x;   // 0..65535, one float4-quad each
    const int wq  = tid & 63;
    const int hh  = (tid >> 6) & (HH - 1);
    const int bb  = tid >> 14;
    const long base = (((long)bb * 9) * HH + hh) * WW + wq * 4;

    float kv[9][4];
    #pragma unroll
    for (int j = 0; j < 9; ++j) {
        const float4 v = *reinterpret_cast<const float4*>(ker + base + (long)j * HH * WW);
        kv[j][0] = v.x; kv[j][1] = v.y; kv[j][2] = v.z; kv[j][3] = v.w;
    }
    #pragma unroll
    for (int p = 0; p < 4; ++p) {
        float m = kv[0][p];
        #pragma unroll
        for (int j = 1; j < 9; ++j) m = fmaxf(m, kv[j][p]);
        float s = 0.f;
        #pragma unroll
        for (int j = 0; j < 9; ++j) { kv[j][p] = __expf(kv[j][p] - m); s += kv[j][p]; }
        const float inv = 1.0f / s;
        #pragma unroll
        for (int j = 0; j < 9; ++j) kv[j][p] *= inv;
    }
    #pragma unroll
    for (int j = 0; j < 9; ++j) {
        vf4 o; o.x = kv[j][0]; o.y = kv[j][1]; o.z = kv[j][2]; o.w = kv[j][3];
        *reinterpret_cast<vf4*>(wsw + base + (long)j * HH * WW) = o;
    }
}

// ---------------- pass 2: conv with precomputed weights ----------------
__global__ __launch_bounds__(256) void conv_kernel(
    const float* __restrict__ x,
    const float* __restrict__ wsr,
    float* __restrict__ out)
{
    __shared__ float lds[CG][NROW][WW];   // 24 KiB

    const int t  = threadIdx.x;
    const int rb = t >> 6;
    const int wq = t & 63;
    const int w0 = wq * 4;

    const int hband = blockIdx.x;   // 0..63
    const int cg    = blockIdx.y;   // 0..15
    const int b     = blockIdx.z;   // 0..3
    const int h0    = hband * RPB;
    const int h     = h0 + rb;

    const long cs = (long)HH * WW;
    const float* xb = x   + (((long)b * CHAN + cg * CG) * cs);
    float*       ob = out + (((long)b * CHAN + cg * CG) * cs);

    // issue all 24 row-DMAs (6 per wave), zero VGPR held
    #pragma unroll
    for (int k = 0; k < (CG * NROW) / RPB; ++k) {
        const int idx  = k * RPB + rb;
        const int ch   = idx / NROW;
        const int slot = idx % NROW;
        int g = h0 - 1 + slot;
        g = (g < 0) ? 1 : ((g > HH - 1) ? HH - 2 : g);
        const float* gsrc = xb + (long)ch * cs + (long)g * WW + w0;
        __builtin_amdgcn_global_load_lds((gas_ptr)gsrc, (las_ptr)&lds[ch][slot][0], 16, 0, 0);
    }

    // weight loads (L2/L3-hot, no dependent compute) overlap the DMAs
    float kv[9][4];
    const long kbase = (((long)b * 9) * HH + h) * WW + w0;
    #pragma unroll
    for (int j = 0; j < 9; ++j) {
        const float4 v = *reinterpret_cast<const float4*>(wsr + kbase + (long)j * HH * WW);
        kv[j][0] = v.x; kv[j][1] = v.y; kv[j][2] = v.z; kv[j][3] = v.w;
    }

    __syncthreads();   // drains DMA + weight loads, rows visible across waves

    // conv from LDS; halo via direct LDS reads (no shuffles, no divergence)
    #pragma unroll
    for (int i = 0; i < CG; ++i) {
        float acc0 = 0.f, acc1 = 0.f, acc2 = 0.f, acc3 = 0.f;
        #pragma unroll
        for (int r = 0; r < 3; ++r) {
            const float* lrow = &lds[i][rb + r][0];
            const float4 v = *reinterpret_cast<const float4*>(lrow + w0);
            const float lft = lrow[(wq == 0)  ? 1      : w0 - 1];
            const float rgt = lrow[(wq == 63) ? WW - 2 : w0 + 4];
            const float vals[6] = { lft, v.x, v.y, v.z, v.w, rgt };
            #pragma unroll
            for (int dx = 0; dx < 3; ++dx) {
                const int j = r * 3 + dx;
                acc0 = fmaf(kv[j][0], vals[0 + dx], acc0);
                acc1 = fmaf(kv[j][1], vals[1 + dx], acc1);
                acc2 = fmaf(kv[j][2], vals[2 + dx], acc2);
                acc3 = fmaf(kv[j][3], vals[3 + dx], acc3);
            }
        }
        vf4 o; o.x = acc0; o.y = acc1; o.z = acc2; o.w = acc3;
        __builtin_nontemporal_store(o, reinterpret_cast<vf4*>(ob + (long)i * cs + (long)h * WW + w0));
    }
}

// ---------------- fallback: fused single-pass (round-8 kernel) ----------------
__global__ __launch_bounds__(256) void dynconv_fused_kernel(
    const float* __restrict__ x,
    const float* __restrict__ ker,
    float* __restrict__ out)
{
    __shared__ float lds[CG][NROW][WW];

    const int t  = threadIdx.x;
    const int rb = t >> 6;
    const int wq = t & 63;
    const int w0 = wq * 4;

    const int hband = blockIdx.x;
    const int cg    = blockIdx.y;
    const int b     = blockIdx.z;
    const int h0    = hband * RPB;
    const int h     = h0 + rb;

    const long cs = (long)HH * WW;
    const float* xb = x   + (((long)b * CHAN + cg * CG) * cs);
    float*       ob = out + (((long)b * CHAN + cg * CG) * cs);

    #pragma unroll
    for (int k = 0; k < (CG * NROW) / RPB; ++k) {
        const int idx  = k * RPB + rb;
        const int ch   = idx / NROW;
        const int slot = idx % NROW;
        int g = h0 - 1 + slot;
        g = (g < 0) ? 1 : ((g > HH - 1) ? HH - 2 : g);
        const float* gsrc = xb + (long)ch * cs + (long)g * WW + w0;
        __builtin_amdgcn_global_load_lds((gas_ptr)gsrc, (las_ptr)&lds[ch][slot][0], 16, 0, 0);
    }

    float kv[9][4];
    const long kbase = (((long)b * 9) * HH + h) * WW + w0;
    #pragma unroll
    for (int j = 0; j < 9; ++j) {
        const float4 v = *reinterpret_cast<const float4*>(ker + kbase + (long)j * HH * WW);
        kv[j][0] = v.x; kv[j][1] = v.y; kv[j][2] = v.z; kv[j][3] = v.w;
    }
    #pragma unroll
    for (int p = 0; p < 4; ++p) {
        float m = kv[0][p];
        #pragma unroll
        for (int j = 1; j < 9; ++j) m = fmaxf(m, kv[j][p]);
        float s = 0.f;
        #pragma unroll
        for (int j = 0; j < 9; ++j) { kv[j][p] = __expf(kv[j][p] - m); s += kv[j][p]; }
        const float inv = 1.0f / s;
        #pragma unroll
        for (int j = 0; j < 9; ++j) kv[j][p] *= inv;
    }

    __syncthreads();

    #pragma unroll
    for (int i = 0; i < CG; ++i) {
        float acc0 = 0.f, acc1 = 0.f, acc2 = 0.f, acc3 = 0.f;
        #pragma unroll
        for (int r = 0; r < 3; ++r) {
            const float* lrow = &lds[i][rb + r][0];
            const float4 v = *reinterpret_cast<const float4*>(lrow + w0);
            const float lft = lrow[(wq == 0)  ? 1      : w0 - 1];
            const float rgt = lrow[(wq == 63) ? WW - 2 : w0 + 4];
            const float vals[6] = { lft, v.x, v.y, v.z, v.w, rgt };
            #pragma unroll
            for (int dx = 0; dx < 3; ++dx) {
                const int j = r * 3 + dx;
                acc0 = fmaf(kv[j][0], vals[0 + dx], acc0);
                acc1 = fmaf(kv[j][1], vals[1 + dx], acc1);
                acc2 = fmaf(kv[j][2], vals[2 + dx], acc2);
                acc3 = fmaf(kv[j][3], vals[3 + dx], acc3);
            }
        }
        vf4 o; o.x = acc0; o.y = acc1; o.z = acc2; o.w = acc3;
        __builtin_nontemporal_store(o, reinterpret_cast<vf4*>(ob + (long)i * cs + (long)h * WW + w0));
    }
}

extern "C" void kernel_launch(void* const* d_in, const int* in_sizes, int n_in,
                              void* d_out, int out_size, void* d_ws, size_t ws_size,
                              hipStream_t stream) {
    const float* x   = (const float*)d_in[0];
    const float* ker = (const float*)d_in[1];
    float* out = (float*)d_out;

    if (ws_size >= WS_ELEMS * sizeof(float)) {
        float* wsw = (float*)d_ws;
        softmax_kernel<<<dim3(256), dim3(256), 0, stream>>>(ker, wsw);
        dim3 grid(HH / RPB, CHAN / CG, BATCH);  // (64, 16, 4)
        conv_kernel<<<grid, dim3(256), 0, stream>>>(x, wsw, out);
    } else {
        dim3 grid(HH / RPB, CHAN / CG, BATCH);
        dynconv_fused_kernel<<<grid, dim3(256), 0, stream>>>(x, ker, out);
    }
}

// Round 10
// 28.654 us; speedup vs baseline: 1.3639x; 1.3639x over previous
//
#include <hip/hip_runtime.h>
#include <stdint.h>

// Dynamic 3x3 softmax-weighted conv, reflect padding. Fused single pass,
// LDS DMA staging, XCD-chunked block swizzle for L2/HBM locality.
// x: (4, 64, 256, 256) f32, kernel: (4, 9, 256, 256) f32, out: (4, 64, 256, 256) f32

constexpr int BATCH = 4;
constexpr int CHAN  = 64;
constexpr int HH    = 256;
constexpr int WW    = 256;
constexpr int CG    = 4;        // channels per block
constexpr int RPB   = 4;        // output rows per block (one wave per row)
constexpr int NROW  = RPB + 2;  // staged input rows per channel
constexpr int NWG   = (HH / RPB) * (CHAN / CG) * BATCH;  // 4096
constexpr int NXCD  = 8;
constexpr int CPX   = NWG / NXCD;                        // 512 (exact: 4096%8==0)

typedef float vf4 __attribute__((ext_vector_type(4)));
typedef const __attribute__((address_space(1))) void* gas_ptr;
typedef __attribute__((address_space(3))) void* las_ptr;

__global__ __launch_bounds__(256) void dynconv_kernel(
    const float* __restrict__ x,
    const float* __restrict__ ker,
    float* __restrict__ out)
{
    __shared__ float lds[CG][NROW][WW];   // 24 KiB

    // ---- XCD-chunked bijective swizzle: each XCD sweeps a contiguous
    // hband-major span (all 64 hbands of a (cg,b) slice back-to-back) ----
    const int id   = blockIdx.x;
    const int work = (id & (NXCD - 1)) * CPX + (id >> 3);
    const int hband = work & 63;           // fastest: contiguous rows
    const int cg    = (work >> 6) & 15;
    const int b     = work >> 10;

    const int t  = threadIdx.x;
    const int rb = t >> 6;          // wave id = output row in band
    const int wq = t & 63;          // lane = float4 slot
    const int w0 = wq * 4;
    const int h0 = hband * RPB;
    const int h  = h0 + rb;

    const long cs = (long)HH * WW;
    const float* xb = x   + (((long)b * CHAN + cg * CG) * cs);
    float*       ob = out + (((long)b * CHAN + cg * CG) * cs);

    // ---- issue all 24 row-DMAs (6 per wave), zero VGPR held ----
    #pragma unroll
    for (int k = 0; k < (CG * NROW) / RPB; ++k) {
        const int idx  = k * RPB + rb;
        const int ch   = idx / NROW;
        const int slot = idx % NROW;
        int g = h0 - 1 + slot;
        g = (g < 0) ? 1 : ((g > HH - 1) ? HH - 2 : g);
        const float* gsrc = xb + (long)ch * cs + (long)g * WW + w0;
        __builtin_amdgcn_global_load_lds((gas_ptr)gsrc, (las_ptr)&lds[ch][slot][0], 16, 0, 0);
    }

    // ---- kernel loads + softmax overlap the DMA latency ----
    float kv[9][4];
    const long kbase = (((long)b * 9) * HH + h) * WW + w0;
    #pragma unroll
    for (int j = 0; j < 9; ++j) {
        const float4 v = *reinterpret_cast<const float4*>(ker + kbase + (long)j * HH * WW);
        kv[j][0] = v.x; kv[j][1] = v.y; kv[j][2] = v.z; kv[j][3] = v.w;
    }
    #pragma unroll
    for (int p = 0; p < 4; ++p) {
        float m = kv[0][p];
        #pragma unroll
        for (int j = 1; j < 9; ++j) m = fmaxf(m, kv[j][p]);
        float s = 0.f;
        #pragma unroll
        for (int j = 0; j < 9; ++j) { kv[j][p] = __expf(kv[j][p] - m); s += kv[j][p]; }
        const float inv = 1.0f / s;
        #pragma unroll
        for (int j = 0; j < 9; ++j) kv[j][p] *= inv;
    }

    __syncthreads();   // drains DMA, rows visible across waves

    // ---- conv from LDS; halo via direct LDS reads ----
    #pragma unroll
    for (int i = 0; i < CG; ++i) {
        float acc0 = 0.f, acc1 = 0.f, acc2 = 0.f, acc3 = 0.f;
        #pragma unroll
        for (int r = 0; r < 3; ++r) {
            const float* lrow = &lds[i][rb + r][0];
            const float4 v = *reinterpret_cast<const float4*>(lrow + w0);
            const float lft = lrow[(wq == 0)  ? 1      : w0 - 1];
            const float rgt = lrow[(wq == 63) ? WW - 2 : w0 + 4];
            const float vals[6] = { lft, v.x, v.y, v.z, v.w, rgt };
            #pragma unroll
            for (int dx = 0; dx < 3; ++dx) {
                const int j = r * 3 + dx;
                acc0 = fmaf(kv[j][0], vals[0 + dx], acc0);
                acc1 = fmaf(kv[j][1], vals[1 + dx], acc1);
                acc2 = fmaf(kv[j][2], vals[2 + dx], acc2);
                acc3 = fmaf(kv[j][3], vals[3 + dx], acc3);
            }
        }
        vf4 o; o.x = acc0; o.y = acc1; o.z = acc2; o.w = acc3;
        __builtin_nontemporal_store(o, reinterpret_cast<vf4*>(ob + (long)i * cs + (long)h * WW + w0));
    }
}

extern "C" void kernel_launch(void* const* d_in, const int* in_sizes, int n_in,
                              void* d_out, int out_size, void* d_ws, size_t ws_size,
                              hipStream_t stream) {
    const float* x   = (const float*)d_in[0];
    const float* ker = (const float*)d_in[1];
    float* out = (float*)d_out;

    dynconv_kernel<<<dim3(NWG), dim3(256), 0, stream>>>(x, ker, out);
}

// Round 11
// 27.794 us; speedup vs baseline: 1.4062x; 1.0310x over previous
//
#include <hip/hip_runtime.h>
#include <stdint.h>

// Dynamic 3x3 softmax-weighted conv, reflect padding. Fused single pass,
// LDS DMA staging, XCD-chunked block swizzle, shuffle halo (bank-conflict-free).
// x: (4, 64, 256, 256) f32, kernel: (4, 9, 256, 256) f32, out: (4, 64, 256, 256) f32

constexpr int BATCH = 4;
constexpr int CHAN  = 64;
constexpr int HH    = 256;
constexpr int WW    = 256;
constexpr int CG    = 4;        // channels per block
constexpr int RPB   = 4;        // output rows per block (one wave per row)
constexpr int NROW  = RPB + 2;  // staged input rows per channel
constexpr int NWG   = (HH / RPB) * (CHAN / CG) * BATCH;  // 4096
constexpr int NXCD  = 8;
constexpr int CPX   = NWG / NXCD;                        // 512 (exact: 4096%8==0)

typedef float vf4 __attribute__((ext_vector_type(4)));
typedef const __attribute__((address_space(1))) void* gas_ptr;
typedef __attribute__((address_space(3))) void* las_ptr;

__global__ __launch_bounds__(256) void dynconv_kernel(
    const float* __restrict__ x,
    const float* __restrict__ ker,
    float* __restrict__ out)
{
    __shared__ float lds[CG][NROW][WW];   // 24 KiB

    // ---- XCD-chunked bijective swizzle: each XCD sweeps a contiguous
    // hband-major span (all 64 hbands of a (cg,b) slice back-to-back) ----
    const int id   = blockIdx.x;
    const int work = (id & (NXCD - 1)) * CPX + (id >> 3);
    const int hband = work & 63;           // fastest: contiguous rows
    const int cg    = (work >> 6) & 15;
    const int b     = work >> 10;

    const int t  = threadIdx.x;
    const int rb = t >> 6;          // wave id = output row in band
    const int wq = t & 63;          // lane = float4 slot
    const int w0 = wq * 4;
    const int h0 = hband * RPB;
    const int h  = h0 + rb;

    const long cs = (long)HH * WW;
    const float* xb = x   + (((long)b * CHAN + cg * CG) * cs);
    float*       ob = out + (((long)b * CHAN + cg * CG) * cs);

    // ---- issue all 24 row-DMAs (6 per wave), zero VGPR held ----
    #pragma unroll
    for (int k = 0; k < (CG * NROW) / RPB; ++k) {
        const int idx  = k * RPB + rb;
        const int ch   = idx / NROW;
        const int slot = idx % NROW;
        int g = h0 - 1 + slot;
        g = (g < 0) ? 1 : ((g > HH - 1) ? HH - 2 : g);
        const float* gsrc = xb + (long)ch * cs + (long)g * WW + w0;
        __builtin_amdgcn_global_load_lds((gas_ptr)gsrc, (las_ptr)&lds[ch][slot][0], 16, 0, 0);
    }

    // ---- kernel loads + softmax overlap the DMA latency ----
    float kv[9][4];
    const long kbase = (((long)b * 9) * HH + h) * WW + w0;
    #pragma unroll
    for (int j = 0; j < 9; ++j) {
        const float4 v = *reinterpret_cast<const float4*>(ker + kbase + (long)j * HH * WW);
        kv[j][0] = v.x; kv[j][1] = v.y; kv[j][2] = v.z; kv[j][3] = v.w;
    }
    #pragma unroll
    for (int p = 0; p < 4; ++p) {
        float m = kv[0][p];
        #pragma unroll
        for (int j = 1; j < 9; ++j) m = fmaxf(m, kv[j][p]);
        float s = 0.f;
        #pragma unroll
        for (int j = 0; j < 9; ++j) { kv[j][p] = __expf(kv[j][p] - m); s += kv[j][p]; }
        const float inv = 1.0f / s;
        #pragma unroll
        for (int j = 0; j < 9; ++j) kv[j][p] *= inv;
    }

    __syncthreads();   // drains DMA, rows visible across waves

    // ---- conv from LDS; halo via cross-lane shuffle (no bank conflicts) ----
    #pragma unroll
    for (int i = 0; i < CG; ++i) {
        float acc0 = 0.f, acc1 = 0.f, acc2 = 0.f, acc3 = 0.f;
        #pragma unroll
        for (int r = 0; r < 3; ++r) {
            const float4 v = *reinterpret_cast<const float4*>(&lds[i][rb + r][w0]);
            float lft = __shfl_up(v.w, 1);
            if (wq == 0)  lft = v.y;     // reflect x[-1] -> x[1]
            float rgt = __shfl_down(v.x, 1);
            if (wq == 63) rgt = v.z;     // reflect x[256] -> x[254]
            const float vals[6] = { lft, v.x, v.y, v.z, v.w, rgt };
            #pragma unroll
            for (int dx = 0; dx < 3; ++dx) {
                const int j = r * 3 + dx;
                acc0 = fmaf(kv[j][0], vals[0 + dx], acc0);
                acc1 = fmaf(kv[j][1], vals[1 + dx], acc1);
                acc2 = fmaf(kv[j][2], vals[2 + dx], acc2);
                acc3 = fmaf(kv[j][3], vals[3 + dx], acc3);
            }
        }
        vf4 o; o.x = acc0; o.y = acc1; o.z = acc2; o.w = acc3;
        __builtin_nontemporal_store(o, reinterpret_cast<vf4*>(ob + (long)i * cs + (long)h * WW + w0));
    }
}

extern "C" void kernel_launch(void* const* d_in, const int* in_sizes, int n_in,
                              void* d_out, int out_size, void* d_ws, size_t ws_size,
                              hipStream_t stream) {
    const float* x   = (const float*)d_in[0];
    const float* ker = (const float*)d_in[1];
    float* out = (float*)d_out;

    dynconv_kernel<<<dim3(NWG), dim3(256), 0, stream>>>(x, ker, out);
}